// Round 1
// baseline (1171.041 us; speedup 1.0000x reference)
//
#include <hip/hip_runtime.h>
#include <math.h>

#define BB 16
#define TT 2048
#define CC 1024
#define HH 64
#define MTOT (BB*TT)

// ---------------- Kernel 1: QKV projection GEMM ----------------
// out[m][n] = (sum_k x[m][k] * W[k][n] + b[n]) * scale
// BM=128, BN=64(=H), BK=64; 256 threads; micro-tile 8 rows x 4 cols.
#define BM1 128
#define BK1 64

__global__ __launch_bounds__(256) void qkv_kernel(
    const float* __restrict__ x,
    const float* __restrict__ Wq, const float* __restrict__ bq,
    const float* __restrict__ Wk, const float* __restrict__ bk,
    const float* __restrict__ Wv, const float* __restrict__ bv,
    float* __restrict__ ws)
{
    // pad rows to 68 floats: 68*4B = 272B = 17*16B -> float4-aligned rows,
    // bank-quad rotates by 1 per row (17 mod 8) -> spreads LDS banks.
    __shared__ float Xs[BM1][BK1 + 4];
    __shared__ float Wt[BK1][HH + 4];

    const int which = blockIdx.y;
    const float* W; const float* bias; float scale; float* dst;
    if (which == 0)      { W = Wq; bias = bq; scale = 0.125f; dst = ws; }                      // q (scale=1/sqrt(64))
    else if (which == 1) { W = Wk; bias = bk; scale = 1.0f;   dst = ws + (size_t)MTOT*HH; }    // k
    else                 { W = Wv; bias = bv; scale = 1.0f;   dst = ws + (size_t)2*MTOT*HH; }  // v

    const int tid = threadIdx.x;
    const int tx = tid & 15;   // col group: cols 4*tx .. 4*tx+3
    const int ty = tid >> 4;   // row group: rows 8*ty .. 8*ty+7
    const int m0 = blockIdx.x * BM1;

    float4 acc[8];
    #pragma unroll
    for (int i = 0; i < 8; ++i) acc[i] = make_float4(0.f, 0.f, 0.f, 0.f);

    for (int k0 = 0; k0 < CC; k0 += BK1) {
        // stage X tile: 128x64 = 2048 float4, 8 per thread, coalesced
        #pragma unroll
        for (int p = 0; p < 8; ++p) {
            int idx = p*256 + tid;
            int r = idx >> 4, c4 = idx & 15;
            *(float4*)&Xs[r][c4*4] =
                *(const float4*)(x + (size_t)(m0 + r)*CC + k0 + c4*4);
        }
        // stage W tile: 64x64 = 1024 float4, 4 per thread, coalesced
        #pragma unroll
        for (int p = 0; p < 4; ++p) {
            int idx = p*256 + tid;
            int r = idx >> 4, c4 = idx & 15;
            *(float4*)&Wt[r][c4*4] =
                *(const float4*)(W + (size_t)(k0 + r)*HH + c4*4);
        }
        __syncthreads();

        #pragma unroll
        for (int k4 = 0; k4 < BK1/4; ++k4) {
            float4 xv[8];
            #pragma unroll
            for (int i = 0; i < 8; ++i)
                xv[i] = *(float4*)&Xs[ty*8 + i][k4*4];
            #pragma unroll
            for (int kk = 0; kk < 4; ++kk) {
                float4 wv = *(float4*)&Wt[k4*4 + kk][tx*4];
                #pragma unroll
                for (int i = 0; i < 8; ++i) {
                    float a = (kk == 0) ? xv[i].x : (kk == 1) ? xv[i].y
                             : (kk == 2) ? xv[i].z : xv[i].w;
                    acc[i].x = fmaf(a, wv.x, acc[i].x);
                    acc[i].y = fmaf(a, wv.y, acc[i].y);
                    acc[i].z = fmaf(a, wv.z, acc[i].z);
                    acc[i].w = fmaf(a, wv.w, acc[i].w);
                }
            }
        }
        __syncthreads();
    }

    float4 bias4 = *(const float4*)(bias + tx*4);
    #pragma unroll
    for (int i = 0; i < 8; ++i) {
        int row = m0 + ty*8 + i;
        float4 o;
        o.x = (acc[i].x + bias4.x) * scale;
        o.y = (acc[i].y + bias4.y) * scale;
        o.z = (acc[i].z + bias4.z) * scale;
        o.w = (acc[i].w + bias4.w) * scale;
        *(float4*)(dst + (size_t)row*HH + tx*4) = o;
    }
}

// ---------------- Kernel 2: causal flash attention ----------------
// One block per (batch, 64-row Q tile); online softmax over 32-row K/V tiles.
#define BQ 64
#define BS 32

__global__ __launch_bounds__(256) void attn_kernel(
    const float* __restrict__ ws, float* __restrict__ out)
{
    const float* qp = ws;
    const float* kp = ws + (size_t)MTOT*HH;
    const float* vp = ws + (size_t)2*MTOT*HH;

    __shared__ float Qs[BQ][HH + 4];   // 17408 B
    __shared__ float Ks[BS][HH + 4];   //  8704 B
    __shared__ float Vs[BS][HH + 4];   //  8704 B
    __shared__ float Ss[BQ][BS + 4];   //  9216 B
    __shared__ float mrow[BQ], lrow[BQ], arow[BQ];   // 768 B  (total 44800 B)

    const int tid = threadIdx.x;
    const int tx = tid & 15;   // GEMM2 col group over h; GEMM1 col group over s (2 cols)
    const int ty = tid >> 4;   // row group: q rows 4*ty .. 4*ty+3
    const int b  = blockIdx.y;
    const int q0 = blockIdx.x * BQ;

    // stage Q tile once: 64x64 = 1024 float4
    #pragma unroll
    for (int p = 0; p < 4; ++p) {
        int idx = p*256 + tid;
        int r = idx >> 4, c4 = idx & 15;
        *(float4*)&Qs[r][c4*4] =
            *(const float4*)(qp + ((size_t)b*TT + q0 + r)*HH + c4*4);
    }
    if (tid < BQ) { mrow[tid] = -INFINITY; lrow[tid] = 0.f; arow[tid] = 0.f; }

    float4 oacc[4];
    #pragma unroll
    for (int i = 0; i < 4; ++i) oacc[i] = make_float4(0.f, 0.f, 0.f, 0.f);

    const int nst = (q0 + BQ) / BS;   // last s-tile index touching this q tile, +1

    for (int st = 0; st < nst; ++st) {
        const int s0 = st * BS;
        __syncthreads();   // previous iter done with Ks/Vs/Ss (and Q staged)

        // stage K,V tiles: 32x64 = 512 float4 each, 2 per thread each
        #pragma unroll
        for (int p = 0; p < 2; ++p) {
            int idx = p*256 + tid;
            int r = idx >> 4, c4 = idx & 15;
            *(float4*)&Ks[r][c4*4] =
                *(const float4*)(kp + ((size_t)b*TT + s0 + r)*HH + c4*4);
            *(float4*)&Vs[r][c4*4] =
                *(const float4*)(vp + ((size_t)b*TT + s0 + r)*HH + c4*4);
        }
        __syncthreads();

        // GEMM1: S[64][32] = Q @ K^T  (q already carries 1/sqrt(H))
        // micro: 4 q-rows (ty) x 2 s-cols (tx)
        float2 sacc[4];
        #pragma unroll
        for (int i = 0; i < 4; ++i) sacc[i] = make_float2(0.f, 0.f);
        #pragma unroll
        for (int h4 = 0; h4 < HH/4; ++h4) {
            float4 kv0 = *(float4*)&Ks[2*tx + 0][h4*4];
            float4 kv1 = *(float4*)&Ks[2*tx + 1][h4*4];
            #pragma unroll
            for (int i = 0; i < 4; ++i) {
                float4 qv = *(float4*)&Qs[4*ty + i][h4*4];
                sacc[i].x = fmaf(qv.x, kv0.x, fmaf(qv.y, kv0.y,
                            fmaf(qv.z, kv0.z, fmaf(qv.w, kv0.w, sacc[i].x))));
                sacc[i].y = fmaf(qv.x, kv1.x, fmaf(qv.y, kv1.y,
                            fmaf(qv.z, kv1.z, fmaf(qv.w, kv1.w, sacc[i].y))));
            }
        }
        // causal mask + write S tile
        #pragma unroll
        for (int i = 0; i < 4; ++i) {
            int gq = q0 + 4*ty + i;
            float2 sv;
            sv.x = (s0 + 2*tx + 0 <= gq) ? sacc[i].x : -INFINITY;
            sv.y = (s0 + 2*tx + 1 <= gq) ? sacc[i].y : -INFINITY;
            *(float2*)&Ss[4*ty + i][2*tx] = sv;
        }
        __syncthreads();

        // online softmax: wave w owns rows 16w..16w+15; lanes = 2 rows x 32 cols
        {
            const int lane = tid & 63;
            const int w    = tid >> 6;
            const int colg = lane & 31;
            const int rowg = lane >> 5;
            #pragma unroll
            for (int p = 0; p < 8; ++p) {
                int r = w*16 + p*2 + rowg;
                float val = Ss[r][colg];
                float tmax = val;
                #pragma unroll
                for (int off = 16; off >= 1; off >>= 1)
                    tmax = fmaxf(tmax, __shfl_xor(tmax, off));
                float m_old = mrow[r];
                float m_new = fmaxf(m_old, tmax);       // finite: col 0 valid in tile 0
                float pexp  = __expf(val - m_new);      // masked -> exp(-inf)=0
                float psum  = pexp;
                #pragma unroll
                for (int off = 16; off >= 1; off >>= 1)
                    psum += __shfl_xor(psum, off);
                Ss[r][colg] = pexp;
                if (colg == 0) {
                    float alpha = __expf(m_old - m_new);  // first tile: exp(-inf)=0
                    mrow[r] = m_new;
                    arow[r] = alpha;
                    lrow[r] = alpha * lrow[r] + psum;
                }
            }
        }
        __syncthreads();

        // rescale O, then GEMM2: O[64][64] += P[64][32] @ V[32][64]
        #pragma unroll
        for (int i = 0; i < 4; ++i) {
            float a = arow[4*ty + i];
            oacc[i].x *= a; oacc[i].y *= a; oacc[i].z *= a; oacc[i].w *= a;
        }
        #pragma unroll
        for (int s4 = 0; s4 < BS/4; ++s4) {
            float4 pv[4];
            #pragma unroll
            for (int i = 0; i < 4; ++i)
                pv[i] = *(float4*)&Ss[4*ty + i][s4*4];
            #pragma unroll
            for (int kk = 0; kk < 4; ++kk) {
                float4 vv = *(float4*)&Vs[s4*4 + kk][tx*4];
                #pragma unroll
                for (int i = 0; i < 4; ++i) {
                    float p = (kk == 0) ? pv[i].x : (kk == 1) ? pv[i].y
                             : (kk == 2) ? pv[i].z : pv[i].w;
                    oacc[i].x = fmaf(p, vv.x, oacc[i].x);
                    oacc[i].y = fmaf(p, vv.y, oacc[i].y);
                    oacc[i].z = fmaf(p, vv.z, oacc[i].z);
                    oacc[i].w = fmaf(p, vv.w, oacc[i].w);
                }
            }
        }
    }

    // epilogue: divide by l, store (lrow visible: last write precedes the
    // __syncthreads before the final GEMM2)
    #pragma unroll
    for (int i = 0; i < 4; ++i) {
        float inv = 1.0f / lrow[4*ty + i];
        float4 o;
        o.x = oacc[i].x * inv; o.y = oacc[i].y * inv;
        o.z = oacc[i].z * inv; o.w = oacc[i].w * inv;
        *(float4*)(out + ((size_t)b*TT + q0 + 4*ty + i)*HH + tx*4) = o;
    }
}

extern "C" void kernel_launch(void* const* d_in, const int* in_sizes, int n_in,
                              void* d_out, int out_size, void* d_ws, size_t ws_size,
                              hipStream_t stream) {
    const float* x  = (const float*)d_in[0];
    const float* Wq = (const float*)d_in[1];
    const float* bq = (const float*)d_in[2];
    const float* Wk = (const float*)d_in[3];
    const float* bk = (const float*)d_in[4];
    const float* Wv = (const float*)d_in[5];
    const float* bv = (const float*)d_in[6];
    float* ws  = (float*)d_ws;      // q | k | v planes, 3 * 8 MiB = 24 MiB
    float* out = (float*)d_out;

    dim3 g1(MTOT / BM1, 3);
    qkv_kernel<<<g1, 256, 0, stream>>>(x, Wq, bq, Wk, bk, Wv, bv, ws);

    dim3 g2(TT / BQ, BB);
    attn_kernel<<<g2, 256, 0, stream>>>(ws, out);
}

// Round 2
// 264.583 us; speedup vs baseline: 4.4260x; 4.4260x over previous
//
#include <hip/hip_runtime.h>
#include <math.h>

#define BB 16
#define TT 2048
#define CC 1024
#define HH 64
#define MTOT (BB*TT)

typedef _Float16 f16;
typedef _Float16 f16x8 __attribute__((ext_vector_type(8)));
typedef float f32x4 __attribute__((ext_vector_type(4)));

// ws layout (f16 element offsets):
//   Wt[192][1024]  (n_global-major: rows 0-63 Wq^T, 64-127 Wk^T, 128-191 Wv^T)
//   q  [32768][64] (row-major, pre-scaled by 1/8)
//   k  [32768][64] (row-major)
//   vT [64][32768] (h-major transposed)
#define WT_OFF 0
#define Q_OFF  196608
#define K_OFF  (Q_OFF + (size_t)MTOT*HH)
#define VT_OFF (K_OFF + (size_t)MTOT*HH)

// ---------------- Kernel 0: W transpose+convert ----------------
__global__ __launch_bounds__(256) void prep_kernel(
    const float* __restrict__ Wq, const float* __restrict__ Wk,
    const float* __restrict__ Wv, f16* __restrict__ wt)
{
    int e = blockIdx.x * 256 + threadIdx.x;      // 196608 elems
    int ng = e >> 10, k = e & 1023;
    int which = ng >> 6, n = ng & 63;
    const float* W = (which == 0) ? Wq : (which == 1) ? Wk : Wv;
    wt[e] = (f16)W[k * HH + n];
}

// ---------------- Kernel 1: fused QKV projection (MFMA f16) ----------------
// BM=64 rows/block, N=192 (q|k|v), BK=64. 256 thr = 4 waves; wave w owns
// m-rows 16w..16w+15, computing 12 n-tiles of 16 (acc 12 x f32x4 = 48 VGPR).
#define BM1 64

__global__ __launch_bounds__(256) void qkv_kernel(
    const float* __restrict__ x,
    const float* __restrict__ bq, const float* __restrict__ bk,
    const float* __restrict__ bv,
    const f16* __restrict__ wt, f16* __restrict__ ws)
{
    __shared__ f16 Xs[BM1][72];    // +8 pad: rows 144B -> bank-quad rotate
    __shared__ f16 Ws[192][72];
    __shared__ f16 Vt[HH][72];     // v transpose staging

    const int tid  = threadIdx.x;
    const int lane = tid & 63, w = tid >> 6;
    const int c = lane & 15, g = lane >> 4;
    const int m0 = blockIdx.x * BM1;

    f32x4 acc[12];
    #pragma unroll
    for (int i = 0; i < 12; ++i) acc[i] = (f32x4){0.f, 0.f, 0.f, 0.f};

    for (int k0 = 0; k0 < CC; k0 += 64) {
        __syncthreads();
        // stage x tile 64x64 fp32 -> f16 LDS (4 float4/thread, coalesced)
        #pragma unroll
        for (int p = 0; p < 4; ++p) {
            int idx = p * 256 + tid;
            int r = idx >> 4, c4 = idx & 15;
            float4 v = *(const float4*)(x + (size_t)(m0 + r) * CC + k0 + c4 * 4);
            f16 t4[4] = {(f16)v.x, (f16)v.y, (f16)v.z, (f16)v.w};
            *(uint2*)&Xs[r][c4 * 4] = *(uint2*)t4;
        }
        // stage Wt tile 192x64 f16 (6 x 16B/thread)
        #pragma unroll
        for (int p = 0; p < 6; ++p) {
            int idx = p * 256 + tid;
            int r = idx >> 3, ch = idx & 7;
            *(f16x8*)&Ws[r][ch * 8] = *(const f16x8*)(wt + (size_t)r * CC + k0 + ch * 8);
        }
        __syncthreads();

        #pragma unroll
        for (int kk = 0; kk < 2; ++kk) {
            f16x8 a = *(f16x8*)&Xs[w * 16 + c][kk * 32 + g * 8];
            #pragma unroll
            for (int nt = 0; nt < 12; ++nt) {
                f16x8 b = *(f16x8*)&Ws[nt * 16 + c][kk * 32 + g * 8];
                acc[nt] = __builtin_amdgcn_mfma_f32_16x16x32_f16(a, b, acc[nt], 0, 0, 0);
            }
        }
    }

    // epilogue: q,k direct (C/D layout row = 4g+r, col = nt*16+c)
    #pragma unroll
    for (int nt = 0; nt < 8; ++nt) {
        int whichp = nt >> 2;               // 0=q, 1=k
        int h = (nt & 3) * 16 + c;
        float bias  = whichp ? bk[h] : bq[h];
        float scale = whichp ? 1.0f : 0.125f;   // fold 1/sqrt(64) into q
        f16* plane = ws + (whichp ? K_OFF : Q_OFF);
        #pragma unroll
        for (int r = 0; r < 4; ++r) {
            int m = m0 + w * 16 + g * 4 + r;
            plane[(size_t)m * HH + h] = (f16)((acc[nt][r] + bias) * scale);
        }
    }
    // v: transpose through LDS, then coalesced global write to vT[h][m]
    #pragma unroll
    for (int nt = 8; nt < 12; ++nt) {
        int h = (nt - 8) * 16 + c;
        float bias = bv[h];
        #pragma unroll
        for (int r = 0; r < 4; ++r)
            Vt[h][w * 16 + g * 4 + r] = (f16)(acc[nt][r] + bias);
    }
    __syncthreads();
    {
        int h = tid >> 2, part = tid & 3;   // 4 threads/row, 16 elems each
        f16x8 a0 = *(f16x8*)&Vt[h][part * 16];
        f16x8 a1 = *(f16x8*)&Vt[h][part * 16 + 8];
        f16* dst = ws + VT_OFF + (size_t)h * MTOT + m0 + part * 16;
        *(f16x8*)dst = a0;
        *(f16x8*)(dst + 8) = a1;
    }
}

// ---------------- Kernel 2: causal flash attention (MFMA f16) ----------------
// BQ=BS=64. 4 waves; wave w owns q-rows 16w..16w+15. Softmax state (m,l)
// lives in registers in C/D layout (replicated across the 16-lane group).
#define BQ 64
#define BS 64

__global__ __launch_bounds__(256) void attn_kernel(
    const f16* __restrict__ ws, float* __restrict__ out)
{
    const f16* qp = ws + Q_OFF;
    const f16* kp = ws + K_OFF;
    const f16* vt = ws + VT_OFF;

    __shared__ f16 Qs[BQ][72];
    __shared__ f16 Ks[BS][72];
    __shared__ f16 Vs[HH][72];   // Vs[h][s]
    __shared__ f16 Ps[BQ][72];   // P round-trip: C/D -> A layout

    const int tid  = threadIdx.x;
    const int lane = tid & 63, w = tid >> 6;
    const int c = lane & 15, g = lane >> 4;
    const int b = blockIdx.y;
    // makespan balance: co-resident pair (x, x+256) gets qi and 31-qi
    const int qi = ((b >> 3) & 1) ? ((int)gridDim.x - 1 - (int)blockIdx.x)
                                  : (int)blockIdx.x;
    const int q0 = qi * BQ;
    const size_t rowbase = (size_t)b * TT;

    // stage Q once (2 x 16B/thread)
    #pragma unroll
    for (int p = 0; p < 2; ++p) {
        int idx = p * 256 + tid;
        int r = idx >> 3, ch = idx & 7;
        *(f16x8*)&Qs[r][ch * 8] = *(const f16x8*)(qp + (rowbase + q0 + r) * HH + ch * 8);
    }

    f32x4 o[4];
    #pragma unroll
    for (int i = 0; i < 4; ++i) o[i] = (f32x4){0.f, 0.f, 0.f, 0.f};
    float m[4] = {-INFINITY, -INFINITY, -INFINITY, -INFINITY};
    float l[4] = {0.f, 0.f, 0.f, 0.f};

    const int nst = qi + 1;
    for (int st = 0; st < nst; ++st) {
        const int s0 = st * BS;
        __syncthreads();   // protect Ks/Vs/Ps from previous iteration's reads
        #pragma unroll
        for (int p = 0; p < 2; ++p) {
            int idx = p * 256 + tid;
            int r = idx >> 3, ch = idx & 7;
            *(f16x8*)&Ks[r][ch * 8] = *(const f16x8*)(kp + (rowbase + s0 + r) * HH + ch * 8);
            *(f16x8*)&Vs[r][ch * 8] = *(const f16x8*)(vt + (size_t)r * MTOT + rowbase + s0 + ch * 8);
        }
        __syncthreads();

        // S = Q K^T  (q pre-scaled): 8 mfma
        f32x4 s[4];
        #pragma unroll
        for (int nt = 0; nt < 4; ++nt) s[nt] = (f32x4){0.f, 0.f, 0.f, 0.f};
        f16x8 a0 = *(f16x8*)&Qs[w * 16 + c][g * 8];
        f16x8 a1 = *(f16x8*)&Qs[w * 16 + c][32 + g * 8];
        #pragma unroll
        for (int nt = 0; nt < 4; ++nt) {
            f16x8 b0 = *(f16x8*)&Ks[nt * 16 + c][g * 8];
            f16x8 b1 = *(f16x8*)&Ks[nt * 16 + c][32 + g * 8];
            s[nt] = __builtin_amdgcn_mfma_f32_16x16x32_f16(a0, b0, s[nt], 0, 0, 0);
            s[nt] = __builtin_amdgcn_mfma_f32_16x16x32_f16(a1, b1, s[nt], 0, 0, 0);
        }

        // causal mask: only the diagonal tile (s0 == q0)
        if (st == nst - 1) {
            #pragma unroll
            for (int nt = 0; nt < 4; ++nt)
                #pragma unroll
                for (int r = 0; r < 4; ++r)
                    if (nt * 16 + c > w * 16 + g * 4 + r) s[nt][r] = -INFINITY;
        }

        // online softmax in C/D register layout (row = 4g+r across lane group)
        float alpha[4];
        #pragma unroll
        for (int r = 0; r < 4; ++r) {
            float t = fmaxf(fmaxf(s[0][r], s[1][r]), fmaxf(s[2][r], s[3][r]));
            #pragma unroll
            for (int off = 8; off >= 1; off >>= 1)
                t = fmaxf(t, __shfl_xor(t, off));
            float mn = fmaxf(m[r], t);
            alpha[r] = __expf(m[r] - mn);   // first tile: exp(-inf)=0
            m[r] = mn;
        }
        float rs[4] = {0.f, 0.f, 0.f, 0.f};
        #pragma unroll
        for (int nt = 0; nt < 4; ++nt)
            #pragma unroll
            for (int r = 0; r < 4; ++r) {
                float p = __expf(s[nt][r] - m[r]);   // masked -> exp(-inf)=0
                s[nt][r] = p;
                rs[r] += p;
            }
        #pragma unroll
        for (int r = 0; r < 4; ++r) {
            #pragma unroll
            for (int off = 8; off >= 1; off >>= 1)
                rs[r] += __shfl_xor(rs[r], off);
            l[r] = alpha[r] * l[r] + rs[r];
        }

        // P: C/D -> LDS (A layout source); rescale O
        #pragma unroll
        for (int nt = 0; nt < 4; ++nt)
            #pragma unroll
            for (int r = 0; r < 4; ++r)
                Ps[w * 16 + g * 4 + r][nt * 16 + c] = (f16)s[nt][r];
        #pragma unroll
        for (int nt = 0; nt < 4; ++nt)
            #pragma unroll
            for (int r = 0; r < 4; ++r)
                o[nt][r] *= alpha[r];
        __syncthreads();

        // O += P V : 8 mfma
        f16x8 pa0 = *(f16x8*)&Ps[w * 16 + c][g * 8];
        f16x8 pa1 = *(f16x8*)&Ps[w * 16 + c][32 + g * 8];
        #pragma unroll
        for (int nt = 0; nt < 4; ++nt) {
            f16x8 vb0 = *(f16x8*)&Vs[nt * 16 + c][g * 8];
            f16x8 vb1 = *(f16x8*)&Vs[nt * 16 + c][32 + g * 8];
            o[nt] = __builtin_amdgcn_mfma_f32_16x16x32_f16(pa0, vb0, o[nt], 0, 0, 0);
            o[nt] = __builtin_amdgcn_mfma_f32_16x16x32_f16(pa1, vb1, o[nt], 0, 0, 0);
        }
    }

    // epilogue: O / l -> fp32 out (16 lanes/row = 64B coalesced segments)
    #pragma unroll
    for (int r = 0; r < 4; ++r) {
        float inv = 1.0f / l[r];
        int mrow = q0 + w * 16 + g * 4 + r;
        #pragma unroll
        for (int nt = 0; nt < 4; ++nt)
            out[(rowbase + mrow) * HH + nt * 16 + c] = o[nt][r] * inv;
    }
}

extern "C" void kernel_launch(void* const* d_in, const int* in_sizes, int n_in,
                              void* d_out, int out_size, void* d_ws, size_t ws_size,
                              hipStream_t stream) {
    const float* x  = (const float*)d_in[0];
    const float* Wq = (const float*)d_in[1];
    const float* bq = (const float*)d_in[2];
    const float* Wk = (const float*)d_in[3];
    const float* bk = (const float*)d_in[4];
    const float* Wv = (const float*)d_in[5];
    const float* bv = (const float*)d_in[6];
    f16*   ws  = (f16*)d_ws;
    float* out = (float*)d_out;

    prep_kernel<<<768, 256, 0, stream>>>(Wq, Wk, Wv, ws + WT_OFF);
    qkv_kernel<<<MTOT / BM1, 256, 0, stream>>>(x, bq, bk, bv, ws + WT_OFF, ws);
    dim3 g2(TT / BQ, BB);
    attn_kernel<<<g2, 256, 0, stream>>>(ws, out);
}